// Round 2
// baseline (302.248 us; speedup 1.0000x reference)
//
#include <hip/hip_runtime.h>
#include <hip/hip_bf16.h>

typedef __attribute__((ext_vector_type(8))) short short8;
typedef __attribute__((ext_vector_type(4))) float f32x4;

static constexpr int NN = 64;
static constexpr int C  = 128;
static constexpr int H  = 56;
static constexpr int W  = 56;
static constexpr int HP = 58;          // padded spatial extent
static constexpr int KTOT = 1152;      // 9 * 128

__device__ __forceinline__ void gload16(const void* g, void* l) {
    __builtin_amdgcn_global_load_lds(
        (const __attribute__((address_space(1))) unsigned int*)g,
        (__attribute__((address_space(3))) unsigned int*)l, 16, 0, 0);
}

// ---------------------------------------------------------------------------
// Pack weights: w[o][c][kh][kw] * scale[o] -> Wp[o][tap*128 + c] (bf16),
// shift[o] = beta - mean*scale.  grid=128 (o), block=128 (c).
// ---------------------------------------------------------------------------
__global__ __launch_bounds__(128)
void pack_weights(const float* __restrict__ w, const float* __restrict__ g,
                  const float* __restrict__ b, const float* __restrict__ m,
                  const float* __restrict__ v, __hip_bfloat16* __restrict__ Wp,
                  float* __restrict__ shift)
{
    int o = blockIdx.x;
    int c = threadIdx.x;
    float scale = g[o] * rsqrtf(v[o] + 1e-5f);
    if (c == 0) shift[o] = b[o] - m[o] * scale;
    const float* ws = w + ((size_t)o * C + c) * 9;
    #pragma unroll
    for (int tap = 0; tap < 9; ++tap)
        Wp[(size_t)o * KTOT + tap * C + c] = __float2bfloat16(ws[tap] * scale);
}

// ---------------------------------------------------------------------------
// NCHW fp32 -> padded NHWC bf16.  grid = N*H blocks, 256 threads.
// ---------------------------------------------------------------------------
__global__ __launch_bounds__(256)
void transform_x(const float* __restrict__ x, __hip_bfloat16* __restrict__ Xp)
{
    __shared__ float t[C * 57];          // pitch 57 -> conflict-free both phases
    int bid = blockIdx.x;
    int n = bid / H, h = bid % H;
    int tid = threadIdx.x;

    #pragma unroll
    for (int i = 0; i < 7; ++i) {
        int idx4 = i * 256 + tid;                 // 0..1791 float4s
        int c  = idx4 / 14;
        int wq = (idx4 % 14) * 4;
        const float* p = x + ((size_t)(n * C + c)) * (H * W) + h * W + wq;
        float4 vv = *(const float4*)p;
        t[c * 57 + wq + 0] = vv.x;
        t[c * 57 + wq + 1] = vv.y;
        t[c * 57 + wq + 2] = vv.z;
        t[c * 57 + wq + 3] = vv.w;
    }
    __syncthreads();
    #pragma unroll
    for (int i = 0; i < 28; ++i) {
        int idx = i * 256 + tid;                  // 0..7167
        int c = idx & 127, w = idx >> 7;
        float vv = t[c * 57 + w];
        Xp[(((size_t)n * HP + (h + 1)) * HP + (w + 1)) * C + c] = __float2bfloat16(vv);
    }
}

// ---------------------------------------------------------------------------
// Implicit-GEMM 3x3 conv, TWO (n,h) output rows per block: M=128 (2x64,
// 56 valid each) x O=128.  X staged in a 2-slot ring (1 new row per kh),
// weights staged per tap.  XOR swizzle byte^=((row&15)<<4) applied on the
// pre-swizzled global SOURCE (linear gload_lds dest) and on LDS reads.
// WHICH==0: D[m][o] -> relu(D+shift) -> NHWC bf16 padded (Y1)
// WHICH==1: D[o][m] -> relu(D+shift+identity) -> NCHW fp32
// ---------------------------------------------------------------------------
template<int WHICH>
__global__ __launch_bounds__(256)
void conv3x3_kernel(const __hip_bfloat16* __restrict__ Xp,
                    const __hip_bfloat16* __restrict__ Wp,
                    const float* __restrict__ shift,
                    const float* __restrict__ ident,
                    void* __restrict__ outp)
{
    __shared__ char s_x[2][64 * 256];   // ring: [slot][x-pos 0..63][128 c] bf16
    __shared__ char s_w[128 * 256];     // [o][128 c] bf16 (one tap)

    const int tid  = threadIdx.x;
    const int wave = tid >> 6;
    const int lane = tid & 63;
    const int lr = lane & 15, lg = lane >> 4;

    const int bid = blockIdx.x;
    const int n = bid / 28, h0 = (bid % 28) * 2;

    // padded input row (h0 + q) base, q = 0..3
    const char* xbase = (const char*)Xp + ((size_t)n * HP + h0) * (HP * 256);

    // prologue: stage input rows q=0 -> slot0, q=1 -> slot1 (32 x 1KB blocks)
    #pragma unroll
    for (int i = 0; i < 8; ++i) {
        int t = wave + i * 4;            // 0..31
        int q = t >> 4, blk = t & 15;
        int dst = blk * 1024 + lane * 16;
        int src = dst ^ (((dst >> 8) & 15) << 4);
        gload16(xbase + (size_t)q * (HP * 256) + src, s_x[q] + blk * 1024);
    }

    f32x4 acc[16];
    #pragma unroll
    for (int i = 0; i < 16; ++i) acc[i] = (f32x4){0.f, 0.f, 0.f, 0.f};

    for (int kh = 0; kh < 3; ++kh) {
        for (int kw = 0; kw < 3; ++kw) {
            const int tap = kh * 3 + kw;
            // stage weight tap slice [128 o][128 c] (32 KB)
            const char* wt = (const char*)Wp + tap * 256;
            #pragma unroll
            for (int i = 0; i < 8; ++i) {
                int blk = wave * 8 + i;
                int dst = blk * 1024 + lane * 16;
                int o   = dst >> 8;
                int col = (dst & 255) ^ ((o & 15) << 4);
                gload16(wt + (size_t)o * (KTOT * 2) + col, s_w + blk * 1024);
            }
            __syncthreads();

            #pragma unroll
            for (int kb = 0; kb < 4; ++kb) {
                const int cb = kb * 64 + lg * 16;     // c byte offset
                short8 xa[8], wb[2];
                #pragma unroll
                for (int sm = 0; sm < 8; ++sm) {
                    int row  = (sm & 3) * 16 + lr + kw;        // x position
                    int slot = (kh + (sm >> 2)) & 1;
                    int off  = ((row << 8) + cb) ^ ((row & 15) << 4);
                    xa[sm] = *(const short8*)(s_x[slot] + off);
                }
                #pragma unroll
                for (int so = 0; so < 2; ++so) {
                    int o   = wave * 32 + so * 16 + lr;
                    int off = ((o << 8) + cb) ^ ((o & 15) << 4);
                    wb[so] = *(const short8*)(s_w + off);
                }
                #pragma unroll
                for (int sm = 0; sm < 8; ++sm)
                    #pragma unroll
                    for (int so = 0; so < 2; ++so) {
                        if (WHICH == 0)
                            acc[sm * 2 + so] = __builtin_amdgcn_mfma_f32_16x16x32_bf16(
                                xa[sm], wb[so], acc[sm * 2 + so], 0, 0, 0);
                        else
                            acc[so * 8 + sm] = __builtin_amdgcn_mfma_f32_16x16x32_bf16(
                                wb[so], xa[sm], acc[so * 8 + sm], 0, 0, 0);
                    }
            }
            __syncthreads();
        }
        // ring-stage next input row q=kh+2 into slot (kh&1); drained by the
        // vmcnt(0) preceding the next tap's first barrier.
        if (kh < 2) {
            #pragma unroll
            for (int i = 0; i < 4; ++i) {
                int blk = wave + i * 4;          // 0..15
                int dst = blk * 1024 + lane * 16;
                int src = dst ^ (((dst >> 8) & 15) << 4);
                gload16(xbase + (size_t)(kh + 2) * (HP * 256) + src,
                        s_x[kh & 1] + blk * 1024);
            }
        }
    }

    if (WHICH == 0) {
        // D[m][o]: m = sm*16 + lg*4 + r, o = wave*32 + so*16 + lr
        __hip_bfloat16* o1 = (__hip_bfloat16*)outp;
        #pragma unroll
        for (int so = 0; so < 2; ++so) {
            int o = wave * 32 + so * 16 + lr;
            float sh = shift[o];
            #pragma unroll
            for (int sm = 0; sm < 8; ++sm) {
                f32x4 vv = acc[sm * 2 + so];
                int out_r = sm >> 2;
                size_t rowbase = ((size_t)n * HP + (h0 + out_r + 1)) * HP;
                #pragma unroll
                for (int r = 0; r < 4; ++r) {
                    int w = (sm & 3) * 16 + lg * 4 + r;
                    if (w < W) {
                        float f = vv[r] + sh;
                        f = f > 0.f ? f : 0.f;
                        o1[(rowbase + (w + 1)) * C + o] = __float2bfloat16(f);
                    }
                }
            }
        }
    } else {
        // D[o][m]: o = wave*32 + so*16 + lg*4 + r, m = sm*16 + lr
        float* o2 = (float*)outp;
        #pragma unroll
        for (int so = 0; so < 2; ++so) {
            int obase = wave * 32 + so * 16 + lg * 4;
            f32x4 sh4 = *(const f32x4*)(shift + obase);
            #pragma unroll
            for (int sm = 0; sm < 8; ++sm) {
                f32x4 vv = acc[so * 8 + sm];
                int w = (sm & 3) * 16 + lr;
                int h = h0 + (sm >> 2);
                if (w < W) {
                    #pragma unroll
                    for (int r = 0; r < 4; ++r) {
                        int o = obase + r;
                        size_t idx = ((size_t)(n * C + o) * H + h) * W + w;
                        float f = vv[r] + sh4[r] + ident[idx];
                        o2[idx] = f > 0.f ? f : 0.f;
                    }
                }
            }
        }
    }
}

// ---------------------------------------------------------------------------
extern "C" void kernel_launch(void* const* d_in, const int* in_sizes, int n_in,
                              void* d_out, int out_size, void* d_ws, size_t ws_size,
                              hipStream_t stream)
{
    const float* x  = (const float*)d_in[0];
    const float* w1 = (const float*)d_in[1];
    const float* g1 = (const float*)d_in[2];
    const float* b1 = (const float*)d_in[3];
    const float* m1 = (const float*)d_in[4];
    const float* v1 = (const float*)d_in[5];
    const float* w2 = (const float*)d_in[6];
    const float* g2 = (const float*)d_in[7];
    const float* b2 = (const float*)d_in[8];
    const float* m2 = (const float*)d_in[9];
    const float* v2 = (const float*)d_in[10];
    float* out = (float*)d_out;

    char* ws = (char*)d_ws;
    const size_t PADBUF = (size_t)NN * HP * HP * C * 2;   // 55,107,584 B
    size_t oX  = 0;
    size_t oY  = oX + PADBUF + 32768;    // 32 KB slack for staging over-read
    size_t oW1 = oY + PADBUF + 32768;
    size_t oW2 = oW1 + (size_t)C * KTOT * 2;
    size_t oS1 = oW2 + (size_t)C * KTOT * 2;
    size_t oS2 = oS1 + 512;

    __hip_bfloat16* Xp  = (__hip_bfloat16*)(ws + oX);
    __hip_bfloat16* Y1  = (__hip_bfloat16*)(ws + oY);
    __hip_bfloat16* W1p = (__hip_bfloat16*)(ws + oW1);
    __hip_bfloat16* W2p = (__hip_bfloat16*)(ws + oW2);
    float* s1 = (float*)(ws + oS1);
    float* s2 = (float*)(ws + oS2);

    hipMemsetAsync(Xp, 0, PADBUF, stream);
    hipMemsetAsync(Y1, 0, PADBUF, stream);

    pack_weights<<<128, 128, 0, stream>>>(w1, g1, b1, m1, v1, W1p, s1);
    pack_weights<<<128, 128, 0, stream>>>(w2, g2, b2, m2, v2, W2p, s2);
    transform_x<<<NN * H, 256, 0, stream>>>(x, Xp);

    conv3x3_kernel<0><<<NN * 28, 256, 0, stream>>>(Xp, W1p, s1, nullptr, (void*)Y1);
    conv3x3_kernel<1><<<NN * 28, 256, 0, stream>>>(Y1, W2p, s2, x, (void*)out);
}

// Round 3
// 295.837 us; speedup vs baseline: 1.0217x; 1.0217x over previous
//
#include <hip/hip_runtime.h>
#include <hip/hip_bf16.h>

typedef __attribute__((ext_vector_type(8))) short short8;
typedef __attribute__((ext_vector_type(16))) float f32x16;

static constexpr int NN = 64;
static constexpr int C  = 128;
static constexpr int H  = 56;
static constexpr int W  = 56;
static constexpr int HP = 58;          // padded spatial extent
static constexpr int ROWB = HP * 256;  // padded row stride in bytes (NHWC bf16)

__device__ __forceinline__ void gload16(const void* g, void* l) {
    __builtin_amdgcn_global_load_lds(
        (const __attribute__((address_space(1))) unsigned int*)g,
        (__attribute__((address_space(3))) unsigned int*)l, 16, 0, 0);
}

__device__ __forceinline__ f32x16 mfma32(short8 a, short8 b, f32x16 c) {
    return __builtin_amdgcn_mfma_f32_32x32x16_bf16(a, b, c, 0, 0, 0);
}

// ---------------------------------------------------------------------------
// Pack weights into MFMA-fragment order:
//   Wp2[((tap*8 + ks)*2 + hi)*128 + o][j]  (bf16, j=0..7)
// holding w[o][c][tap]*scale[o] with c = ks*16 + hi*8 + j.
// A wave's B-fragment (32 consecutive o, one hi) is then 512 B contiguous.
// shift[o] = beta - mean*scale.  grid=128 (o), block=128 (c).
// ---------------------------------------------------------------------------
__global__ __launch_bounds__(128)
void pack_weights(const float* __restrict__ w, const float* __restrict__ g,
                  const float* __restrict__ b, const float* __restrict__ m,
                  const float* __restrict__ v, __hip_bfloat16* __restrict__ Wp2,
                  float* __restrict__ shift)
{
    int o = blockIdx.x;
    int c = threadIdx.x;
    float scale = g[o] * rsqrtf(v[o] + 1e-5f);
    if (c == 0) shift[o] = b[o] - m[o] * scale;
    const float* ws = w + ((size_t)o * C + c) * 9;
    int ks = c >> 4, hi = (c >> 3) & 1, j = c & 7;
    #pragma unroll
    for (int tap = 0; tap < 9; ++tap) {
        size_t idx = ((((size_t)tap * 8 + ks) * 2 + hi) * 128 + o) * 8 + j;
        Wp2[idx] = __float2bfloat16(ws[tap] * scale);
    }
}

// ---------------------------------------------------------------------------
// NCHW fp32 -> padded NHWC bf16.  grid = N*H blocks, 256 threads.
// ---------------------------------------------------------------------------
__global__ __launch_bounds__(256)
void transform_x(const float* __restrict__ x, __hip_bfloat16* __restrict__ Xp)
{
    __shared__ float t[C * 57];          // pitch 57 -> conflict-free both phases
    int bid = blockIdx.x;
    int n = bid / H, h = bid % H;
    int tid = threadIdx.x;

    #pragma unroll
    for (int i = 0; i < 7; ++i) {
        int idx4 = i * 256 + tid;                 // 0..1791 float4s
        int c  = idx4 / 14;
        int wq = (idx4 % 14) * 4;
        const float* p = x + ((size_t)(n * C + c)) * (H * W) + h * W + wq;
        float4 vv = *(const float4*)p;
        t[c * 57 + wq + 0] = vv.x;
        t[c * 57 + wq + 1] = vv.y;
        t[c * 57 + wq + 2] = vv.z;
        t[c * 57 + wq + 3] = vv.w;
    }
    __syncthreads();
    #pragma unroll
    for (int i = 0; i < 28; ++i) {
        int idx = i * 256 + tid;                  // 0..7167
        int c = idx & 127, w = idx >> 7;
        float vv = t[c * 57 + w];
        Xp[(((size_t)n * HP + (h + 1)) * HP + (w + 1)) * C + c] = __float2bfloat16(vv);
    }
}

// ---------------------------------------------------------------------------
// Implicit-GEMM 3x3 conv.  Block = 256 thr (4 waves), 2 output rows (h0,h0+1)
// x O=128.  Wave (wm,wo) owns row h0+wm, o in [wo*64, wo*64+64): a 64x64
// tile of 2x2 32x32x16-MFMA fragments (acc = 64 VGPR).
// X: 3-slot LDS ring of padded input rows (64 pos x 128c, XOR-swizzled
// byte^=((pos&15)<<4) via pre-swizzled gload_lds source).  1 barrier per kh.
// W: NO LDS — fragment-ordered Wp2 read directly via coalesced 16B loads
// (L2/L1-resident, 288 KB total).
// WHICH==0: D[m][o] -> relu(D+shift) -> NHWC bf16 padded (Y1)
// WHICH==1: D[o][m] -> relu(D+shift+identity) -> NCHW fp32
// ---------------------------------------------------------------------------
template<int WHICH>
__global__ __launch_bounds__(256, 3)
void conv3x3_kernel(const __hip_bfloat16* __restrict__ Xp,
                    const __hip_bfloat16* __restrict__ Wp2,
                    const float* __restrict__ shift,
                    const float* __restrict__ ident,
                    void* __restrict__ outp)
{
    __shared__ char s_x[3 * 16384 + 1024];   // 3 ring slots + over-read pad

    const int tid  = threadIdx.x;
    const int wave = tid >> 6;
    const int lane = tid & 63;
    const int lr5  = lane & 31;
    const int hi   = lane >> 5;
    const int wm   = wave >> 1;      // which output row
    const int wo   = wave & 1;       // which o-half

    const int bid = blockIdx.x;
    const int n = bid / 28, h0 = (bid % 28) * 2;

    const char* xbase = (const char*)Xp + ((size_t)n * HP + h0) * ROWB;

    // prologue: stage padded rows h0+0 -> slot0, h0+1 -> slot1 (32 KB)
    #pragma unroll
    for (int i = 0; i < 8; ++i) {
        int t = wave + i * 4;            // 0..31
        int q = t >> 4, blk = t & 15;
        int dst = blk * 1024 + lane * 16;
        int src = dst ^ (((dst >> 8) & 15) << 4);
        gload16(xbase + (size_t)q * ROWB + src, s_x + q * 16384 + blk * 1024);
    }

    // per-wave W fragment base (in bf16 elements)
    const __hip_bfloat16* wbase = Wp2 + hi * 1024 + (wo * 64 + lr5) * 8;

    f32x16 acc[2][2];
    #pragma unroll
    for (int i = 0; i < 2; ++i)
        #pragma unroll
        for (int j = 0; j < 2; ++j)
            acc[i][j] = f32x16{0,0,0,0,0,0,0,0,0,0,0,0,0,0,0,0};

    __syncthreads();

    for (int kh = 0; kh < 3; ++kh) {
        // ring-prefetch padded row h0+kh+2 into slot (kh+2)%3 (not read
        // this kh; drained by the barrier at end of this kh).
        if (kh < 2) {
            int slot = (kh + 2) % 3;
            #pragma unroll
            for (int i = 0; i < 4; ++i) {
                int blk = wave + i * 4;          // 0..15
                int dst = blk * 1024 + lane * 16;
                int src = dst ^ (((dst >> 8) & 15) << 4);
                gload16(xbase + (size_t)(kh + 2) * ROWB + src,
                        s_x + slot * 16384 + blk * 1024);
            }
        }
        const int sbase = ((kh + wm) % 3) * 16384;
        #pragma unroll
        for (int kw = 0; kw < 3; ++kw) {
            const int tap = kh * 3 + kw;
            const __hip_bfloat16* wt = wbase + (size_t)tap * 16384;
            #pragma unroll
            for (int ks = 0; ks < 8; ++ks) {
                short8 wb0 = *(const short8*)(wt + ks * 2048);
                short8 wb1 = *(const short8*)(wt + ks * 2048 + 256);
                int row0 = lr5 + kw;
                int off0 = (row0 * 256 + ks * 32 + hi * 16) ^ ((row0 & 15) << 4);
                short8 xa0 = *(const short8*)(s_x + sbase + off0);
                int row1 = row0 + 32;
                int off1 = (row1 * 256 + ks * 32 + hi * 16) ^ ((row1 & 15) << 4);
                short8 xa1 = *(const short8*)(s_x + sbase + off1);
                if (WHICH == 0) {
                    acc[0][0] = mfma32(xa0, wb0, acc[0][0]);
                    acc[0][1] = mfma32(xa0, wb1, acc[0][1]);
                    acc[1][0] = mfma32(xa1, wb0, acc[1][0]);
                    acc[1][1] = mfma32(xa1, wb1, acc[1][1]);
                } else {
                    acc[0][0] = mfma32(wb0, xa0, acc[0][0]);
                    acc[0][1] = mfma32(wb0, xa1, acc[0][1]);
                    acc[1][0] = mfma32(wb1, xa0, acc[1][0]);
                    acc[1][1] = mfma32(wb1, xa1, acc[1][1]);
                }
            }
        }
        __syncthreads();
    }

    // C/D layout (32x32): col = lane&31, row = (reg&3) + 8*(reg>>2) + 4*hi
    if (WHICH == 0) {
        // D[m][o]: acc[mf][of]; m-row = x, col = o
        __hip_bfloat16* o1 = (__hip_bfloat16*)outp;
        size_t rowb = ((size_t)n * HP + (h0 + wm + 1)) * HP;
        #pragma unroll
        for (int of = 0; of < 2; ++of) {
            int o = wo * 64 + of * 32 + lr5;
            float sh = shift[o];
            #pragma unroll
            for (int mf = 0; mf < 2; ++mf) {
                #pragma unroll
                for (int r = 0; r < 16; ++r) {
                    int x = mf * 32 + 4 * hi + (r & 3) + 8 * (r >> 2);
                    if (x < W) {
                        float f = acc[mf][of][r] + sh;
                        f = f > 0.f ? f : 0.f;
                        o1[(rowb + x + 1) * C + o] = __float2bfloat16(f);
                    }
                }
            }
        }
    } else {
        // D[o][m]: acc[of][mf]; row = o, col = x
        float* o2 = (float*)outp;
        int h = h0 + wm;
        #pragma unroll
        for (int of = 0; of < 2; ++of) {
            int obase = wo * 64 + of * 32 + 4 * hi;
            #pragma unroll
            for (int mf = 0; mf < 2; ++mf) {
                int x = mf * 32 + lr5;
                if (x < W) {
                    #pragma unroll
                    for (int r = 0; r < 16; ++r) {
                        int o = obase + (r & 3) + 8 * (r >> 2);
                        size_t idx = ((size_t)(n * C + o) * H + h) * W + x;
                        float f = acc[of][mf][r] + shift[o] + ident[idx];
                        o2[idx] = f > 0.f ? f : 0.f;
                    }
                }
            }
        }
    }
}

// ---------------------------------------------------------------------------
extern "C" void kernel_launch(void* const* d_in, const int* in_sizes, int n_in,
                              void* d_out, int out_size, void* d_ws, size_t ws_size,
                              hipStream_t stream)
{
    const float* x  = (const float*)d_in[0];
    const float* w1 = (const float*)d_in[1];
    const float* g1 = (const float*)d_in[2];
    const float* b1 = (const float*)d_in[3];
    const float* m1 = (const float*)d_in[4];
    const float* v1 = (const float*)d_in[5];
    const float* w2 = (const float*)d_in[6];
    const float* g2 = (const float*)d_in[7];
    const float* b2 = (const float*)d_in[8];
    const float* m2 = (const float*)d_in[9];
    const float* v2 = (const float*)d_in[10];
    float* out = (float*)d_out;

    char* ws = (char*)d_ws;
    const size_t PADBUF = (size_t)NN * HP * HP * C * 2;   // 55,107,584 B
    const size_t WBUF   = (size_t)9 * 8 * 2 * 128 * 8 * 2; // 294,912 B
    size_t oX  = 0;
    size_t oY  = oX + PADBUF + 32768;    // slack for staging over-read
    size_t oW1 = oY + PADBUF + 32768;
    size_t oW2 = oW1 + WBUF;
    size_t oS1 = oW2 + WBUF;
    size_t oS2 = oS1 + 512;

    __hip_bfloat16* Xp  = (__hip_bfloat16*)(ws + oX);
    __hip_bfloat16* Y1  = (__hip_bfloat16*)(ws + oY);
    __hip_bfloat16* W1p = (__hip_bfloat16*)(ws + oW1);
    __hip_bfloat16* W2p = (__hip_bfloat16*)(ws + oW2);
    float* s1 = (float*)(ws + oS1);
    float* s2 = (float*)(ws + oS2);

    hipMemsetAsync(Xp, 0, PADBUF, stream);
    hipMemsetAsync(Y1, 0, PADBUF, stream);

    pack_weights<<<128, 128, 0, stream>>>(w1, g1, b1, m1, v1, W1p, s1);
    pack_weights<<<128, 128, 0, stream>>>(w2, g2, b2, m2, v2, W2p, s2);
    transform_x<<<NN * H, 256, 0, stream>>>(x, Xp);

    conv3x3_kernel<0><<<NN * 28, 256, 0, stream>>>(Xp, W1p, s1, nullptr, (void*)Y1);
    conv3x3_kernel<1><<<NN * 28, 256, 0, stream>>>(Y1, W2p, s2, x, (void*)out);
}

// Round 4
// 227.769 us; speedup vs baseline: 1.3270x; 1.2988x over previous
//
#include <hip/hip_runtime.h>
#include <hip/hip_bf16.h>

typedef __attribute__((ext_vector_type(8))) short short8;
typedef __attribute__((ext_vector_type(16))) float f32x16;
typedef __attribute__((ext_vector_type(4))) float f32x4;

static constexpr int NN = 64;
static constexpr int C  = 128;
static constexpr int H  = 56;
static constexpr int W  = 56;
static constexpr int HP = 58;          // padded spatial extent
static constexpr int ROWB = HP * 256;  // padded row stride in bytes (NHWC bf16)

__device__ __forceinline__ void gload16(const void* g, void* l) {
    __builtin_amdgcn_global_load_lds(
        (const __attribute__((address_space(1))) unsigned int*)g,
        (__attribute__((address_space(3))) unsigned int*)l, 16, 0, 0);
}

__device__ __forceinline__ f32x16 mfma32(short8 a, short8 b, f32x16 c) {
    return __builtin_amdgcn_mfma_f32_32x32x16_bf16(a, b, c, 0, 0, 0);
}

// ---------------------------------------------------------------------------
// Pack weights into MFMA-fragment order:
//   Wp2[((tap*8 + ks)*2 + hi)*128 + o][j]  (bf16, j=0..7), c = ks*16+hi*8+j
// (verified layout: round-3 passed with identical pack + direct-load).
// ---------------------------------------------------------------------------
__global__ __launch_bounds__(128)
void pack_weights(const float* __restrict__ w, const float* __restrict__ g,
                  const float* __restrict__ b, const float* __restrict__ m,
                  const float* __restrict__ v, __hip_bfloat16* __restrict__ Wp2,
                  float* __restrict__ shift)
{
    int o = blockIdx.x;
    int c = threadIdx.x;
    float scale = g[o] * rsqrtf(v[o] + 1e-5f);
    if (c == 0) shift[o] = b[o] - m[o] * scale;
    const float* ws = w + ((size_t)o * C + c) * 9;
    int ks = c >> 4, hi = (c >> 3) & 1, j = c & 7;
    #pragma unroll
    for (int tap = 0; tap < 9; ++tap) {
        size_t idx = ((((size_t)tap * 8 + ks) * 2 + hi) * 128 + o) * 8 + j;
        Wp2[idx] = __float2bfloat16(ws[tap] * scale);
    }
}

// ---------------------------------------------------------------------------
// NCHW fp32 -> padded NHWC bf16 (interior only; halo zeroed separately).
// ---------------------------------------------------------------------------
__global__ __launch_bounds__(256)
void transform_x(const float* __restrict__ x, __hip_bfloat16* __restrict__ Xp)
{
    __shared__ float t[C * 57];
    int bid = blockIdx.x;
    int n = bid / H, h = bid % H;
    int tid = threadIdx.x;

    #pragma unroll
    for (int i = 0; i < 7; ++i) {
        int idx4 = i * 256 + tid;
        int c  = idx4 / 14;
        int wq = (idx4 % 14) * 4;
        const float* p = x + ((size_t)(n * C + c)) * (H * W) + h * W + wq;
        float4 vv = *(const float4*)p;
        t[c * 57 + wq + 0] = vv.x;
        t[c * 57 + wq + 1] = vv.y;
        t[c * 57 + wq + 2] = vv.z;
        t[c * 57 + wq + 3] = vv.w;
    }
    __syncthreads();
    #pragma unroll
    for (int i = 0; i < 28; ++i) {
        int idx = i * 256 + tid;
        int c = idx & 127, w = idx >> 7;
        float vv = t[c * 57 + w];
        Xp[(((size_t)n * HP + (h + 1)) * HP + (w + 1)) * C + c] = __float2bfloat16(vv);
    }
}

// ---------------------------------------------------------------------------
// Zero only the halo of a padded NHWC buffer: positions where y==0||57||x==0||57.
// Per n: 228 positions x 256 B.  Each thread writes one 16 B chunk.
// total threads = NN * 228 * 16 = 233472 -> 912 blocks x 256.
// ---------------------------------------------------------------------------
__global__ __launch_bounds__(256)
void zero_halo(__hip_bfloat16* __restrict__ buf)
{
    int idx = blockIdx.x * 256 + threadIdx.x;
    int n = idx / (228 * 16);
    int rem = idx % (228 * 16);
    int p = rem >> 4, l = rem & 15;
    int y, xq;
    if (p < 58)       { y = 0;  xq = p; }
    else if (p < 116) { y = 57; xq = p - 58; }
    else { int q = p - 116; y = 1 + (q >> 1); xq = (q & 1) * 57; }
    short8* dst = (short8*)(buf + (((size_t)n * HP + y) * HP + xq) * C + l * 8);
    *dst = short8{0,0,0,0,0,0,0,0};
}

// ---------------------------------------------------------------------------
// Implicit-GEMM 3x3 conv.  Block = 256 thr (4 waves), 2 output rows x O=128.
// Wave (wm,mh): row h0+wm, m-half mh -> 32 m x 128 o tile = 4 x f32x16 acc.
// X: 3-slot LDS ring (XOR-swizzled via pre-swizzled gload_lds source).
// W: direct from L1/L2 with 2-deep half-tap register prefetch (wqA/wqB).
// WHICH==0: D[m][o] -> relu(D+shift) -> NHWC bf16 padded (Y1)
// WHICH==1: D[o][m] -> relu(D+shift+identity) -> NCHW fp32
// ---------------------------------------------------------------------------
template<int WHICH>
__global__ __launch_bounds__(256, 2)
void conv3x3_kernel(const __hip_bfloat16* __restrict__ Xp,
                    const __hip_bfloat16* __restrict__ Wp2,
                    const float* __restrict__ shift,
                    const float* __restrict__ ident,
                    void* __restrict__ outp)
{
    __shared__ char s_x[3 * 16384 + 1024];   // 3 ring slots + over-read pad

    const int tid  = threadIdx.x;
    const int wave = tid >> 6;
    const int lane = tid & 63;
    const int lr5  = lane & 31;
    const int hi   = lane >> 5;
    const int wm   = wave >> 1;      // output row within block
    const int mh   = wave & 1;       // m-half

    const int bid0 = blockIdx.x;
    const int bid  = (bid0 & 7) * 224 + (bid0 >> 3);   // XCD chunk swizzle
    const int n = bid / 28, h0 = (bid % 28) * 2;

    const char* xbase = (const char*)Xp + ((size_t)n * HP + h0) * ROWB;

    // prologue: stage padded rows 0..2 -> slots 0..2 (48 x 1KB)
    #pragma unroll
    for (int i = 0; i < 12; ++i) {
        int t = wave + i * 4;            // 0..47
        int q = t >> 4, blk = t & 15;
        int dst = blk * 1024 + lane * 16;
        int src = dst ^ (((dst >> 8) & 15) << 4);
        gload16(xbase + (size_t)q * ROWB + src, s_x + q * 16384 + blk * 1024);
    }

    const __hip_bfloat16* wlane = Wp2 + hi * 1024 + lr5 * 8;

    short8 wqA[4][4], wqB[4][4];
    f32x16 acc[4];
    #pragma unroll
    for (int i = 0; i < 4; ++i)
        acc[i] = f32x16{0,0,0,0,0,0,0,0,0,0,0,0,0,0,0,0};

#define WLOAD(BUF, HT) { \
    _Pragma("unroll") for (int i_ = 0; i_ < 4; ++i_) { \
        const __hip_bfloat16* p_ = wlane + ((HT) * 4 + i_) * 2048; \
        _Pragma("unroll") for (int of_ = 0; of_ < 4; ++of_) \
            BUF[i_][of_] = *(const short8*)(p_ + of_ * 256); } }

#define COMPUTE(BUF, HT) { \
    constexpr int tap_ = (HT) >> 1; \
    constexpr int kw_ = tap_ % 3, kh_ = tap_ / 3; \
    const int sb_ = ((kh_ + wm) % 3) * 16384; \
    const int row_ = mh * 32 + lr5 + kw_; \
    const int rb_ = row_ * 256, sw_ = (row_ & 15) << 4; \
    _Pragma("unroll") for (int i_ = 0; i_ < 4; ++i_) { \
        int ks_ = ((HT) & 1) * 4 + i_; \
        short8 xa_ = *(const short8*)(s_x + sb_ + rb_ + ((ks_ * 32 + hi * 16) ^ sw_)); \
        _Pragma("unroll") for (int of_ = 0; of_ < 4; ++of_) { \
            if (WHICH == 0) acc[of_] = mfma32(xa_, BUF[i_][of_], acc[of_]); \
            else            acc[of_] = mfma32(BUF[i_][of_], xa_, acc[of_]); } } }

    WLOAD(wqA, 0);
    __syncthreads();
    // ---- kh = 0 (half-taps 0..5) ----
    WLOAD(wqB, 1);  COMPUTE(wqA, 0);
    WLOAD(wqA, 2);  COMPUTE(wqB, 1);
    WLOAD(wqB, 3);  COMPUTE(wqA, 2);
    WLOAD(wqA, 4);  COMPUTE(wqB, 3);
    WLOAD(wqB, 5);  COMPUTE(wqA, 4);
    WLOAD(wqA, 6);  COMPUTE(wqB, 5);
    __syncthreads();
    // ---- kh = 1 (half-taps 6..11); prefetch padded row 3 -> slot 0 ----
    #pragma unroll
    for (int i = 0; i < 4; ++i) {
        int blk = wave + i * 4;          // 0..15
        int dst = blk * 1024 + lane * 16;
        int src = dst ^ (((dst >> 8) & 15) << 4);
        gload16(xbase + (size_t)3 * ROWB + src, s_x + blk * 1024);
    }
    WLOAD(wqB, 7);  COMPUTE(wqA, 6);
    WLOAD(wqA, 8);  COMPUTE(wqB, 7);
    WLOAD(wqB, 9);  COMPUTE(wqA, 8);
    WLOAD(wqA, 10); COMPUTE(wqB, 9);
    WLOAD(wqB, 11); COMPUTE(wqA, 10);
    WLOAD(wqA, 12); COMPUTE(wqB, 11);
    __syncthreads();
    // ---- kh = 2 (half-taps 12..17) ----
    WLOAD(wqB, 13); COMPUTE(wqA, 12);
    WLOAD(wqA, 14); COMPUTE(wqB, 13);
    WLOAD(wqB, 15); COMPUTE(wqA, 14);
    WLOAD(wqA, 16); COMPUTE(wqB, 15);
    WLOAD(wqB, 17); COMPUTE(wqA, 16);
    COMPUTE(wqB, 17);
#undef WLOAD
#undef COMPUTE

    // C/D layout (32x32): col = lane&31, row = (r&3) + 8*(r>>2) + 4*hi
    if (WHICH == 0) {
        __hip_bfloat16* o1 = (__hip_bfloat16*)outp;
        size_t rowb = ((size_t)n * HP + (h0 + wm + 1)) * HP;
        #pragma unroll
        for (int of = 0; of < 4; ++of) {
            int o = of * 32 + lr5;
            float sh = shift[o];
            #pragma unroll
            for (int r = 0; r < 16; ++r) {
                int m = mh * 32 + 4 * hi + (r & 3) + 8 * (r >> 2);
                if (m < W) {
                    float f = acc[of][r] + sh;
                    f = f > 0.f ? f : 0.f;
                    o1[(rowb + m + 1) * C + o] = __float2bfloat16(f);
                }
            }
        }
    } else {
        float* o2 = (float*)outp;
        int h = h0 + wm;
        int m = mh * 32 + lr5;
        if (m < W) {
            #pragma unroll
            for (int of = 0; of < 4; ++of) {
                #pragma unroll
                for (int q = 0; q < 4; ++q) {
                    f32x4 sh = *(const f32x4*)(shift + of * 32 + 4 * hi + 8 * q);
                    #pragma unroll
                    for (int j = 0; j < 4; ++j) {
                        int o = of * 32 + 4 * hi + 8 * q + j;
                        size_t idx = ((size_t)(n * C + o) * H + h) * W + m;
                        float f = acc[of][q * 4 + j] + sh[j] + ident[idx];
                        o2[idx] = f > 0.f ? f : 0.f;
                    }
                }
            }
        }
    }
}

// ---------------------------------------------------------------------------
extern "C" void kernel_launch(void* const* d_in, const int* in_sizes, int n_in,
                              void* d_out, int out_size, void* d_ws, size_t ws_size,
                              hipStream_t stream)
{
    const float* x  = (const float*)d_in[0];
    const float* w1 = (const float*)d_in[1];
    const float* g1 = (const float*)d_in[2];
    const float* b1 = (const float*)d_in[3];
    const float* m1 = (const float*)d_in[4];
    const float* v1 = (const float*)d_in[5];
    const float* w2 = (const float*)d_in[6];
    const float* g2 = (const float*)d_in[7];
    const float* b2 = (const float*)d_in[8];
    const float* m2 = (const float*)d_in[9];
    const float* v2 = (const float*)d_in[10];
    float* out = (float*)d_out;

    char* ws = (char*)d_ws;
    const size_t PADBUF = (size_t)NN * HP * HP * C * 2;    // 55,107,584 B
    const size_t WBUF   = (size_t)9 * 8 * 2 * 128 * 8 * 2; // 294,912 B
    size_t oX  = 0;
    size_t oY  = oX + PADBUF + 32768;    // slack for staging over-read
    size_t oW1 = oY + PADBUF + 32768;
    size_t oW2 = oW1 + WBUF;
    size_t oS1 = oW2 + WBUF;
    size_t oS2 = oS1 + 512;

    __hip_bfloat16* Xp  = (__hip_bfloat16*)(ws + oX);
    __hip_bfloat16* Y1  = (__hip_bfloat16*)(ws + oY);
    __hip_bfloat16* W1p = (__hip_bfloat16*)(ws + oW1);
    __hip_bfloat16* W2p = (__hip_bfloat16*)(ws + oW2);
    float* s1 = (float*)(ws + oS1);
    float* s2 = (float*)(ws + oS2);

    zero_halo<<<912, 256, 0, stream>>>(Xp);
    zero_halo<<<912, 256, 0, stream>>>(Y1);

    pack_weights<<<128, 128, 0, stream>>>(w1, g1, b1, m1, v1, W1p, s1);
    pack_weights<<<128, 128, 0, stream>>>(w2, g2, b2, m2, v2, W2p, s2);
    transform_x<<<NN * H, 256, 0, stream>>>(x, Xp);

    conv3x3_kernel<0><<<NN * 28, 256, 0, stream>>>(Xp, W1p, s1, nullptr, (void*)Y1);
    conv3x3_kernel<1><<<NN * 28, 256, 0, stream>>>(Y1, W2p, s2, x, (void*)out);
}